// Round 1
// baseline (1547.677 us; speedup 1.0000x reference)
//
#include <hip/hip_runtime.h>
#include <math.h>

// GraphCNN: node embed + edge embed/scatter + 3x GCNConv + JK-cat + mean-pool + MLP
// All f32. N=100000, H=64, L=3, E=1.2M, G=1000 (taken from in_sizes at runtime).

#define ATOM(p, v) unsafeAtomicAdd((p), (v))

// ---------------- node embed: h0 = x @ node_w + node_b  (K=128) ----------------
__global__ __launch_bounds__(256) void k_embed(
    const float* __restrict__ x, const float* __restrict__ w,
    const float* __restrict__ b, float* __restrict__ out, int N) {
  __shared__ __align__(16) float in_lds[64 * 132];
  const int base = blockIdx.x * 64;
  const int t = threadIdx.x;
#pragma unroll
  for (int it = 0; it < 32; ++it) {
    int lin = t + it * 256;
    int r = lin >> 7, c = lin & 127;
    int row = base + r;
    float v = (row < N) ? x[(size_t)row * 128 + c] : 0.f;
    in_lds[r * 132 + c] = v;
  }
  __syncthreads();
  const int j = t & 63;                                  // lane = row within tile
  const int wv = __builtin_amdgcn_readfirstlane(t >> 6); // wave = 16-col slab
  const float* wp = w + wv * 16;
  float acc[16];
#pragma unroll
  for (int c = 0; c < 16; ++c) acc[c] = 0.f;
#pragma unroll
  for (int k4 = 0; k4 < 32; ++k4) {
    float4 a = *(const float4*)&in_lds[j * 132 + k4 * 4];
#pragma unroll
    for (int kk = 0; kk < 4; ++kk) {
      float av = ((const float*)&a)[kk];
      int k = k4 * 4 + kk;
#pragma unroll
      for (int c = 0; c < 16; ++c)
        acc[c] = fmaf(av, wp[k * 64 + c], acc[c]);   // w uniform -> s_load
    }
  }
  int row = base + j;
  if (row < N) {
#pragma unroll
    for (int c4 = 0; c4 < 4; ++c4) {
      float4 o;
#pragma unroll
      for (int q = 0; q < 4; ++q)
        ((float*)&o)[q] = acc[c4 * 4 + q] + b[wv * 16 + c4 * 4 + q];
      *(float4*)&out[(size_t)row * 64 + wv * 16 + c4 * 4] = o;
    }
  }
}

// ------- edge embed: e = ea @ ew + eb; h0[row]+=e; h0[col]+=e; deg[col]+=1 -------
__global__ __launch_bounds__(256) void k_edge(
    const float* __restrict__ ea, const float* __restrict__ ew,
    const float* __restrict__ eb, const int* __restrict__ erow,
    const int* __restrict__ ecol, float* h0, float* deg, int E) {
  int t = blockIdx.x * 256 + threadIdx.x;
  int e = __builtin_amdgcn_readfirstlane(t >> 6);  // one wave per edge
  if (e >= E) return;
  int j = threadIdx.x & 63;
  int r = erow[e], c = ecol[e];
  const float* eap = ea + (size_t)e * 16;          // uniform -> s_load
  float acc = eb[j];
#pragma unroll
  for (int k = 0; k < 16; ++k)
    acc = fmaf(eap[k], ew[k * 64 + j], acc);
  ATOM(&h0[(size_t)r * 64 + j], acc);
  ATOM(&h0[(size_t)c * 64 + j], acc);
  if (j == 0) ATOM(&deg[c], 1.0f);
}

// ---------------- dis = rsqrt(deg + 1) ----------------
__global__ __launch_bounds__(256) void k_dis(const float* deg, float* dis, int N) {
  int n = blockIdx.x * 256 + threadIdx.x;
  if (n < N) dis[n] = 1.0f / sqrtf(deg[n] + 1.0f);
}

// ------- conv GEMM: xw = act(hin) @ w ; agg(inplace)=dis^2*xw ; hj slice -------
// act = identity for layer 1, relu(x + bprev) for layers 2/3 (also written to hj).
// hin and agg may alias (same buffer): reads complete before the barrier,
// each block only touches its own 64 rows.
__global__ __launch_bounds__(256) void k_conv(
    const float* hin, const float* __restrict__ w,
    const float* __restrict__ bprev, const float* __restrict__ dis,
    float* __restrict__ xw, float* agg, float* __restrict__ hjprev, int N) {
  __shared__ __align__(16) float in_lds[64 * 68];
  const int base = blockIdx.x * 64;
  const int t = threadIdx.x;
#pragma unroll
  for (int it = 0; it < 16; ++it) {
    int lin = t + it * 256;
    int r = lin >> 6, c = lin & 63;
    int row = base + r;
    float v = (row < N) ? hin[(size_t)row * 64 + c] : 0.f;
    if (bprev != nullptr) {
      v = fmaxf(v + bprev[c], 0.f);
      if (row < N) hjprev[(size_t)row * 192 + c] = v;
    }
    in_lds[r * 68 + c] = v;
  }
  __syncthreads();
  const int j = t & 63;
  const int wv = __builtin_amdgcn_readfirstlane(t >> 6);
  const float* wp = w + wv * 16;
  float acc[16];
#pragma unroll
  for (int c = 0; c < 16; ++c) acc[c] = 0.f;
#pragma unroll
  for (int k4 = 0; k4 < 16; ++k4) {
    float4 a = *(const float4*)&in_lds[j * 68 + k4 * 4];
#pragma unroll
    for (int kk = 0; kk < 4; ++kk) {
      float av = ((const float*)&a)[kk];
      int k = k4 * 4 + kk;
#pragma unroll
      for (int c = 0; c < 16; ++c)
        acc[c] = fmaf(av, wp[k * 64 + c], acc[c]);
    }
  }
  int row = base + j;
  if (row < N) {
    float d = dis[row];
    float d2 = d * d;
#pragma unroll
    for (int c4 = 0; c4 < 4; ++c4) {
      float4 o, s;
#pragma unroll
      for (int q = 0; q < 4; ++q) {
        ((float*)&o)[q] = acc[c4 * 4 + q];
        ((float*)&s)[q] = d2 * acc[c4 * 4 + q];
      }
      *(float4*)&xw[(size_t)row * 64 + wv * 16 + c4 * 4] = o;
      *(float4*)&agg[(size_t)row * 64 + wv * 16 + c4 * 4] = s;
    }
  }
}

// ------- scatter: agg[col] += dis[row]*dis[col] * xw[row] -------
__global__ __launch_bounds__(256) void k_scatter(
    const float* __restrict__ xw, float* agg, const int* __restrict__ erow,
    const int* __restrict__ ecol, const float* __restrict__ dis, int E) {
  int t = blockIdx.x * 256 + threadIdx.x;
  int e = __builtin_amdgcn_readfirstlane(t >> 6);  // one wave per edge
  if (e >= E) return;
  int j = threadIdx.x & 63;
  int r = erow[e], c = ecol[e];
  float nrm = dis[r] * dis[c];
  ATOM(&agg[(size_t)c * 64 + j], nrm * xw[(size_t)r * 64 + j]);
}

// ------- final activation into last JK slice -------
__global__ __launch_bounds__(256) void k_finact(
    const float* __restrict__ agg, const float* __restrict__ b,
    float* __restrict__ hj128, int N) {
  int t = blockIdx.x * 256 + threadIdx.x;
  int n = t >> 6, j = t & 63;
  if (n < N) hj128[(size_t)n * 192 + j] = fmaxf(agg[(size_t)n * 64 + j] + b[j], 0.f);
}

// ------- mean-pool (batch sorted -> binary search) + classifier -------
__global__ __launch_bounds__(192) void k_pool(
    const float* __restrict__ hj, const int* __restrict__ batch, int N,
    const float* __restrict__ w1, const float* __restrict__ b1,
    const float* __restrict__ w2, const float* __restrict__ b2,
    float* __restrict__ out) {
  __shared__ float pl[192];
  int g = blockIdx.x;
  int t = threadIdx.x;
  int lo = 0, hi = N;
  while (lo < hi) { int m = (lo + hi) >> 1; if (batch[m] < g) lo = m + 1; else hi = m; }
  int start = lo;
  hi = N;
  while (lo < hi) { int m = (lo + hi) >> 1; if (batch[m] < g + 1) lo = m + 1; else hi = m; }
  int end = lo;
  float s = 0.f;
  for (int r = start; r < end; ++r) s += hj[(size_t)r * 192 + t];
  int cnt = end - start;
  pl[t] = s / (float)(cnt > 0 ? cnt : 1);
  __syncthreads();
  if (t < 64) {
    float val = 0.f;
    if (t < 32) {
      float z = b1[t];
#pragma unroll 8
      for (int k = 0; k < 192; ++k) z = fmaf(pl[k], w1[k * 32 + t], z);
      z = fmaxf(z, 0.f);
      val = z * w2[t];
    }
#pragma unroll
    for (int off = 16; off > 0; off >>= 1) val += __shfl_down(val, off);
    if (t == 0) out[g] = val + b2[0];
  }
}

extern "C" void kernel_launch(void* const* d_in, const int* in_sizes, int n_in,
                              void* d_out, int out_size, void* d_ws, size_t ws_size,
                              hipStream_t stream) {
  const float* x      = (const float*)d_in[0];
  const float* ea     = (const float*)d_in[1];
  const float* node_w = (const float*)d_in[2];
  const float* node_b = (const float*)d_in[3];
  const float* edge_w = (const float*)d_in[4];
  const float* edge_b = (const float*)d_in[5];
  const float* conv_w = (const float*)d_in[6];
  const float* conv_b = (const float*)d_in[7];
  const float* w1     = (const float*)d_in[8];
  const float* b1     = (const float*)d_in[9];
  const float* w2     = (const float*)d_in[10];
  const float* b2     = (const float*)d_in[11];
  const int*   ei     = (const int*)d_in[12];
  const int*   batch  = (const int*)d_in[13];

  const int N = in_sizes[0] / 128;
  const int E = in_sizes[12] / 2;
  const int G = out_size;
  const int* erow = ei;
  const int* ecol = ei + E;

  float* ws = (float*)d_ws;
  size_t o = 0;
  float* h0  = ws + o; o += (size_t)N * 64;   // embed output / in-place agg buffer
  float* xw  = ws + o; o += (size_t)N * 64;   // per-layer xw
  float* hj  = ws + o; o += (size_t)N * 192;  // JK concat
  float* dis = ws + o; o += N;
  float* deg = ws + o; o += N;
  float* out = (float*)d_out;

  hipMemsetAsync(deg, 0, (size_t)N * sizeof(float), stream);

  dim3 b256(256);
  k_embed<<<(N + 63) / 64, b256, 0, stream>>>(x, node_w, node_b, h0, N);
  k_edge<<<(E + 3) / 4, b256, 0, stream>>>(ea, edge_w, edge_b, erow, ecol, h0, deg, E);
  k_dis<<<(N + 255) / 256, b256, 0, stream>>>(deg, dis, N);
  for (int l = 0; l < 3; ++l) {
    k_conv<<<(N + 63) / 64, b256, 0, stream>>>(
        h0, conv_w + (size_t)l * 64 * 64,
        l ? conv_b + (size_t)(l - 1) * 64 : nullptr, dis,
        xw, h0, l ? hj + (size_t)(l - 1) * 64 : nullptr, N);
    k_scatter<<<(E + 3) / 4, b256, 0, stream>>>(xw, h0, erow, ecol, dis, E);
  }
  k_finact<<<((long long)N * 64 + 255) / 256, b256, 0, stream>>>(
      h0, conv_b + 2 * 64, hj + 128, N);
  k_pool<<<G, dim3(192), 0, stream>>>(hj, batch, N, w1, b1, w2, b2, out);
}

// Round 2
// 682.255 us; speedup vs baseline: 2.2685x; 2.2685x over previous
//
#include <hip/hip_runtime.h>
#include <math.h>

// GraphCNN v2: atomics eliminated where possible.
//  - edge embed via linearity: scatter 16-dim ea (4x fewer atomics), GEMM after.
//  - conv aggregation via CSR-by-col gather (no atomics), built once, used 3x.

#define ATOM(p, v) unsafeAtomicAdd((p), (v))

// ---------------- node embed: h0 = x @ node_w + node_b  (K=128) ----------------
__global__ __launch_bounds__(256) void k_embed(
    const float* __restrict__ x, const float* __restrict__ w,
    const float* __restrict__ b, float* __restrict__ out, int N) {
  __shared__ __align__(16) float in_lds[64 * 132];
  const int base = blockIdx.x * 64;
  const int t = threadIdx.x;
#pragma unroll
  for (int it = 0; it < 32; ++it) {
    int lin = t + it * 256;
    int r = lin >> 7, c = lin & 127;
    int row = base + r;
    in_lds[r * 132 + c] = (row < N) ? x[(size_t)row * 128 + c] : 0.f;
  }
  __syncthreads();
  const int j = t & 63;
  const int wv = __builtin_amdgcn_readfirstlane(t >> 6);
  const float* wp = w + wv * 16;
  float acc[16];
#pragma unroll
  for (int c = 0; c < 16; ++c) acc[c] = 0.f;
#pragma unroll
  for (int k4 = 0; k4 < 32; ++k4) {
    float4 a = *(const float4*)&in_lds[j * 132 + k4 * 4];
#pragma unroll
    for (int kk = 0; kk < 4; ++kk) {
      float av = ((const float*)&a)[kk];
      int k = k4 * 4 + kk;
#pragma unroll
      for (int c = 0; c < 16; ++c)
        acc[c] = fmaf(av, wp[k * 64 + c], acc[c]);
    }
  }
  int row = base + j;
  if (row < N) {
#pragma unroll
    for (int c4 = 0; c4 < 4; ++c4) {
      float4 o;
#pragma unroll
      for (int q = 0; q < 4; ++q)
        ((float*)&o)[q] = acc[c4 * 4 + q] + b[wv * 16 + c4 * 4 + q];
      *(float4*)&out[(size_t)row * 64 + wv * 16 + c4 * 4] = o;
    }
  }
}

// ------- degree counts: indeg[col]++, outdeg[row]++ -------
__global__ __launch_bounds__(256) void k_count(
    const int* __restrict__ erow, const int* __restrict__ ecol,
    int* indeg, int* outdeg, int E) {
  int e = blockIdx.x * 256 + threadIdx.x;
  if (e < E) {
    atomicAdd(&indeg[ecol[e]], 1);
    atomicAdd(&outdeg[erow[e]], 1);
  }
}

// ------- 16-dim ea scatter (linearity): acc16[row]+=ea[e]; acc16[col]+=ea[e] -------
__global__ __launch_bounds__(256) void k_eagg(
    const float* __restrict__ ea, const int* __restrict__ erow,
    const int* __restrict__ ecol, float* acc16, int E) {
  int t = blockIdx.x * 256 + threadIdx.x;
  int e = t >> 4, k = t & 15;
  if (e >= E) return;
  float v = ea[(size_t)e * 16 + k];
  int r = erow[e], c = ecol[e];
  ATOM(&acc16[(size_t)r * 16 + k], v);
  ATOM(&acc16[(size_t)c * 16 + k], v);
}

// ------- exclusive scan of indeg -> csr_off (3 kernels, chunk=1024) -------
__global__ __launch_bounds__(256) void k_scanA(
    const int* __restrict__ cnt, int* __restrict__ off,
    int* __restrict__ chunk_sum, int N) {
  __shared__ int sc[256];
  int b = blockIdx.x, t = threadIdx.x;
  int i0 = b * 1024 + t * 4;
  int v[4];
  int s = 0;
#pragma unroll
  for (int q = 0; q < 4; ++q) {
    v[q] = (i0 + q < N) ? cnt[i0 + q] : 0;
    s += v[q];
  }
  sc[t] = s;
  __syncthreads();
  for (int d = 1; d < 256; d <<= 1) {
    int x = (t >= d) ? sc[t - d] : 0;
    __syncthreads();
    sc[t] += x;
    __syncthreads();
  }
  int run = sc[t] - s;  // exclusive base for this thread
#pragma unroll
  for (int q = 0; q < 4; ++q) {
    if (i0 + q < N) off[i0 + q] = run;
    run += v[q];
  }
  if (t == 255) chunk_sum[b] = sc[255];
}

__global__ __launch_bounds__(128) void k_scanB(
    const int* __restrict__ chunk_sum, int* __restrict__ chunk_base, int nch) {
  __shared__ int sc[128];
  int t = threadIdx.x;
  int s = (t < nch) ? chunk_sum[t] : 0;
  sc[t] = s;
  __syncthreads();
  for (int d = 1; d < 128; d <<= 1) {
    int x = (t >= d) ? sc[t - d] : 0;
    __syncthreads();
    sc[t] += x;
    __syncthreads();
  }
  if (t < nch) chunk_base[t] = sc[t] - s;
}

__global__ __launch_bounds__(256) void k_scanC(
    int* __restrict__ off, const int* __restrict__ chunk_base,
    int* __restrict__ cursor, int N) {
  int i = blockIdx.x * 256 + threadIdx.x;
  if (i < N) {
    int v = off[i] + chunk_base[i >> 10];
    off[i] = v;
    cursor[i] = v;
  }
}

// ------- CSR fill: src_list[pos++] = row for each edge grouped by col -------
__global__ __launch_bounds__(256) void k_fill(
    const int* __restrict__ erow, const int* __restrict__ ecol,
    int* cursor, int* __restrict__ src_list, int E) {
  int e = blockIdx.x * 256 + threadIdx.x;
  if (e < E) {
    int pos = atomicAdd(&cursor[ecol[e]], 1);
    src_list[pos] = erow[e];
  }
}

// ------- fused edge GEMM: h0 += acc16 @ ew + (indeg+outdeg)*eb ; dis = rsqrt(indeg+1) -------
__global__ __launch_bounds__(256) void k_edgemm(
    const float* __restrict__ acc16, const float* __restrict__ ew,
    const float* __restrict__ eb, const int* __restrict__ indeg,
    const int* __restrict__ outdeg, float* h0, float* __restrict__ dis, int N) {
  int t = blockIdx.x * 256 + threadIdx.x;
  int j = t & 63;
  int n = __builtin_amdgcn_readfirstlane(t >> 6);
  if (n >= N) return;
  int id = indeg[n], od = outdeg[n];
  const float* a = acc16 + (size_t)n * 16;  // wave-uniform -> s_load
  float v = h0[(size_t)n * 64 + j] + (float)(id + od) * eb[j];
#pragma unroll
  for (int k = 0; k < 16; ++k)
    v = fmaf(a[k], ew[k * 64 + j], v);
  h0[(size_t)n * 64 + j] = v;
  if (j == 0) dis[n] = 1.0f / sqrtf((float)id + 1.0f);
}

// ------- conv GEMM: xw = h @ w (64x64 tile, weights via s_load) -------
__global__ __launch_bounds__(256) void k_conv(
    const float* __restrict__ hin, const float* __restrict__ w,
    float* __restrict__ xw, int N) {
  __shared__ __align__(16) float in_lds[64 * 68];
  const int base = blockIdx.x * 64;
  const int t = threadIdx.x;
#pragma unroll
  for (int it = 0; it < 16; ++it) {
    int lin = t + it * 256;
    int r = lin >> 6, c = lin & 63;
    int row = base + r;
    in_lds[r * 68 + c] = (row < N) ? hin[(size_t)row * 64 + c] : 0.f;
  }
  __syncthreads();
  const int j = t & 63;
  const int wv = __builtin_amdgcn_readfirstlane(t >> 6);
  const float* wp = w + wv * 16;
  float acc[16];
#pragma unroll
  for (int c = 0; c < 16; ++c) acc[c] = 0.f;
#pragma unroll
  for (int k4 = 0; k4 < 16; ++k4) {
    float4 a = *(const float4*)&in_lds[j * 68 + k4 * 4];
#pragma unroll
    for (int kk = 0; kk < 4; ++kk) {
      float av = ((const float*)&a)[kk];
      int k = k4 * 4 + kk;
#pragma unroll
      for (int c = 0; c < 16; ++c)
        acc[c] = fmaf(av, wp[k * 64 + c], acc[c]);
    }
  }
  int row = base + j;
  if (row < N) {
#pragma unroll
    for (int c4 = 0; c4 < 4; ++c4) {
      float4 o;
#pragma unroll
      for (int q = 0; q < 4; ++q)
        ((float*)&o)[q] = acc[c4 * 4 + q];
      *(float4*)&xw[(size_t)row * 64 + wv * 16 + c4 * 4] = o;
    }
  }
}

// ------- gather aggregation + relu + bias; writes h0 (dense) and hj slice -------
__global__ __launch_bounds__(256) void k_gather(
    const float* __restrict__ xw, const float* __restrict__ dis,
    const int* __restrict__ csr_off, const int* __restrict__ indeg,
    const int* __restrict__ src_list, const float* __restrict__ b,
    float* __restrict__ h0, float* __restrict__ hj_slice, int N) {
  int t = blockIdx.x * 256 + threadIdx.x;
  int j = t & 63;
  int n = __builtin_amdgcn_readfirstlane(t >> 6);
  if (n >= N) return;
  float dc = dis[n];
  float acc = dc * dc * xw[(size_t)n * 64 + j];
  int off = csr_off[n], cnt = indeg[n];
  int k = 0;
  for (; k + 4 <= cnt; k += 4) {
    int r0 = src_list[off + k], r1 = src_list[off + k + 1];
    int r2 = src_list[off + k + 2], r3 = src_list[off + k + 3];
    float d0 = dis[r0], d1 = dis[r1], d2 = dis[r2], d3 = dis[r3];
    float v0 = xw[(size_t)r0 * 64 + j], v1 = xw[(size_t)r1 * 64 + j];
    float v2 = xw[(size_t)r2 * 64 + j], v3 = xw[(size_t)r3 * 64 + j];
    acc = fmaf(dc * d0, v0, acc);
    acc = fmaf(dc * d1, v1, acc);
    acc = fmaf(dc * d2, v2, acc);
    acc = fmaf(dc * d3, v3, acc);
  }
  for (; k < cnt; ++k) {
    int r = src_list[off + k];
    acc = fmaf(dc * dis[r], xw[(size_t)r * 64 + j], acc);
  }
  float act = fmaxf(acc + b[j], 0.f);
  h0[(size_t)n * 64 + j] = act;
  hj_slice[(size_t)n * 192 + j] = act;
}

// ------- mean-pool (batch sorted -> binary search) + classifier -------
__global__ __launch_bounds__(192) void k_pool(
    const float* __restrict__ hj, const int* __restrict__ batch, int N,
    const float* __restrict__ w1, const float* __restrict__ b1,
    const float* __restrict__ w2, const float* __restrict__ b2,
    float* __restrict__ out) {
  __shared__ float pl[192];
  int g = blockIdx.x;
  int t = threadIdx.x;
  int lo = 0, hi = N;
  while (lo < hi) { int m = (lo + hi) >> 1; if (batch[m] < g) lo = m + 1; else hi = m; }
  int start = lo;
  hi = N;
  while (lo < hi) { int m = (lo + hi) >> 1; if (batch[m] < g + 1) lo = m + 1; else hi = m; }
  int end = lo;
  float s = 0.f;
  for (int r = start; r < end; ++r) s += hj[(size_t)r * 192 + t];
  int cnt = end - start;
  pl[t] = s / (float)(cnt > 0 ? cnt : 1);
  __syncthreads();
  if (t < 64) {
    float val = 0.f;
    if (t < 32) {
      float z = b1[t];
#pragma unroll 8
      for (int k = 0; k < 192; ++k) z = fmaf(pl[k], w1[k * 32 + t], z);
      z = fmaxf(z, 0.f);
      val = z * w2[t];
    }
#pragma unroll
    for (int off = 16; off > 0; off >>= 1) val += __shfl_down(val, off);
    if (t == 0) out[g] = val + b2[0];
  }
}

extern "C" void kernel_launch(void* const* d_in, const int* in_sizes, int n_in,
                              void* d_out, int out_size, void* d_ws, size_t ws_size,
                              hipStream_t stream) {
  const float* x      = (const float*)d_in[0];
  const float* ea     = (const float*)d_in[1];
  const float* node_w = (const float*)d_in[2];
  const float* node_b = (const float*)d_in[3];
  const float* edge_w = (const float*)d_in[4];
  const float* edge_b = (const float*)d_in[5];
  const float* conv_w = (const float*)d_in[6];
  const float* conv_b = (const float*)d_in[7];
  const float* w1     = (const float*)d_in[8];
  const float* b1     = (const float*)d_in[9];
  const float* w2     = (const float*)d_in[10];
  const float* b2     = (const float*)d_in[11];
  const int*   ei     = (const int*)d_in[12];
  const int*   batch  = (const int*)d_in[13];

  const int N = in_sizes[0] / 128;
  const int E = in_sizes[12] / 2;
  const int G = out_size;
  const int* erow = ei;
  const int* ecol = ei + E;

  float* ws = (float*)d_ws;
  size_t o = 0;
  float* h0   = ws + o; o += (size_t)N * 64;
  float* xw   = ws + o; o += (size_t)N * 64;   // also aliased as acc16 (N*16) pre-conv
  float* hj   = ws + o; o += (size_t)N * 192;
  float* dis  = ws + o; o += N;
  int* indeg  = (int*)(ws + o); o += N;
  int* outdeg = (int*)(ws + o); o += N;
  int* csroff = (int*)(ws + o); o += N;
  int* cursor = (int*)(ws + o); o += N;
  int* chsum  = (int*)(ws + o); o += 128;
  int* chbase = (int*)(ws + o); o += 128;
  int* srclst = (int*)(ws + o); o += E;
  float* acc16 = xw;
  float* out = (float*)d_out;

  const int nch = (N + 1023) / 1024;

  hipMemsetAsync(indeg, 0, (size_t)N * sizeof(int), stream);
  hipMemsetAsync(outdeg, 0, (size_t)N * sizeof(int), stream);
  hipMemsetAsync(acc16, 0, (size_t)N * 16 * sizeof(float), stream);

  dim3 b256(256);
  k_embed<<<(N + 63) / 64, b256, 0, stream>>>(x, node_w, node_b, h0, N);
  k_count<<<(E + 255) / 256, b256, 0, stream>>>(erow, ecol, indeg, outdeg, E);
  k_eagg<<<((size_t)E * 16 + 255) / 256, b256, 0, stream>>>(ea, erow, ecol, acc16, E);
  k_scanA<<<nch, b256, 0, stream>>>(indeg, csroff, chsum, N);
  k_scanB<<<1, dim3(128), 0, stream>>>(chsum, chbase, nch);
  k_scanC<<<(N + 255) / 256, b256, 0, stream>>>(csroff, chbase, cursor, N);
  k_fill<<<(E + 255) / 256, b256, 0, stream>>>(erow, ecol, cursor, srclst, E);
  k_edgemm<<<((size_t)N * 64 + 255) / 256, b256, 0, stream>>>(
      acc16, edge_w, edge_b, indeg, outdeg, h0, dis, N);
  for (int l = 0; l < 3; ++l) {
    k_conv<<<(N + 63) / 64, b256, 0, stream>>>(h0, conv_w + (size_t)l * 64 * 64, xw, N);
    k_gather<<<((size_t)N * 64 + 255) / 256, b256, 0, stream>>>(
        xw, dis, csroff, indeg, srclst, conv_b + (size_t)l * 64,
        h0, hj + (size_t)l * 64, N);
  }
  k_pool<<<G, dim3(192), 0, stream>>>(hj, batch, N, w1, b1, w2, b2, out);
}